// Round 5
// baseline (1106.922 us; speedup 1.0000x reference)
//
#include <hip/hip_runtime.h>

// BiCLSTM: S=16,B=4,Cin=32,Co=32,H=W=128. fp32 in/out.
// MFMA implicit-GEMM in FP16 (single term): operand ranges (x~N(0,1), h in (-1,1),
// w~0.05*N(0,1)) make fp16's 2^-11 rel-err beat a 3-term bf16 split at 1/3 the MFMAs.
#define S_ 16
#define B_ 4
#define H_ 128
#define W_ 128
#define HW_ (H_ * W_)

typedef __attribute__((ext_vector_type(8))) _Float16 half8;
typedef __attribute__((ext_vector_type(4))) float f32x4;

__device__ __forceinline__ float sigf(float x) { return 1.f / (1.f + __expf(-x)); }
__device__ __forceinline__ float tanhf_(float x) { return 2.f / (1.f + __expf(-2.f * x)) - 1.f; }

// Pack weights into MFMA B-fragment order as fp16.
// wpk: 2 streams [dir] each [ks=18][nf=8][lane=64][e=8] f16 (147,456 B).
// ks = tap*2 + half; ci = half*32 + (lane>>4)*8 + e; co = nf*16 + (lane&15).
__global__ void prep_pack(const float* __restrict__ Wf, const float* __restrict__ Wb,
                          _Float16* __restrict__ wpk) {
    int id = blockIdx.x * 256 + threadIdx.x;  // 2*18*8*64 = 18432
    if (id >= 18432) return;
    int l = id & 63;
    int nf = (id >> 6) & 7;
    int ks = (id >> 9) % 18;
    int d = id / 9216;
    const float* Wsrc = d ? Wb : Wf;
    int tap = ks >> 1, half = ks & 1;
    int dy = tap / 3, dx = tap - dy * 3;
    int co = nf * 16 + (l & 15);
    _Float16* dst = wpk + (size_t)d * 73728 + ((size_t)(ks * 8 + nf) * 64 + l) * 8;
#pragma unroll
    for (int e = 0; e < 8; ++e) {
        int ci = half * 32 + (l >> 4) * 8 + e;
        dst[e] = (_Float16)Wsrc[((co * 64 + ci) * 3 + dy) * 3 + dx];
    }
}

#define CI_PAD 40  // halves per position: 32 ci + 8 pad (80B = 5 x 16B units -> uniform quads)
#define NPOS 324   // 18x18

__device__ __forceinline__ void stage_pos(_Float16* __restrict__ L,
                                          const float* __restrict__ src,  // 32-ch base
                                          int p, int x0, int y0) {
    int r = p / 18;
    int cc = p - r * 18;
    int gy = y0 + r - 1, gx = x0 + cc - 1;
    bool inb = ((unsigned)gy < 128u) && ((unsigned)gx < 128u);
    const float* g = src + (size_t)gy * W_ + gx;
    _Float16* d = L + p * CI_PAD;
#pragma unroll
    for (int cb = 0; cb < 4; ++cb) {
        half8 v;
#pragma unroll
        for (int e = 0; e < 8; ++e)
            v[e] = (_Float16)(inb ? g[(cb * 8 + e) * HW_] : 0.f);
        *(half8*)(d + cb * 8) = v;
    }
}

__device__ __forceinline__ void compute_half(f32x4 (&acc)[4][8],
                                             const _Float16* __restrict__ L,
                                             const _Float16* __restrict__ w,
                                             int half, int lane, int wq) {
    const int px = lane & 15, kg = lane >> 4;
#pragma unroll 1
    for (int tap = 0; tap < 9; ++tap) {
        int dy = tap / 3, dx = tap - dy * 3;
        half8 a[4];
#pragma unroll
        for (int m = 0; m < 4; ++m) {
            int pos = (wq * 4 + m + dy) * 18 + (px + dx);
            a[m] = *(const half8*)(L + pos * CI_PAD + kg * 8);
        }
        const _Float16* bp = w + (size_t)(tap * 2 + half) * 4096;
#pragma unroll
        for (int nf = 0; nf < 8; ++nf) {
            half8 b = *(const half8*)(bp + ((size_t)nf * 64 + lane) * 8);
#pragma unroll
            for (int m = 0; m < 4; ++m)
                acc[m][nf] = __builtin_amdgcn_mfma_f32_16x16x32_f16(a[m], b, acc[m][nf], 0, 0, 0);
        }
    }
}

// One timestep, both directions. grid (8,8,8): x-tiles, y-tiles, z = dir*4+b.
// h state lives in `out` (h(t-1) = out[t-1] slice, race-free across launches).
__global__ __launch_bounds__(256, 2)
void convlstm_mfma(const float* __restrict__ x, const _Float16* __restrict__ wpk,
                   const float* __restrict__ biasf, const float* __restrict__ biasb,
                   float* __restrict__ cst, float* out, int t) {
    const int zb = blockIdx.z;
    const int dir = zb >> 2;
    const int b = zb & 3;
    const int x0 = blockIdx.x * 16, y0 = blockIdx.y * 16;
    const int ts = dir ? (S_ - 1 - t) : t;

    const float* xt = x + (size_t)(ts * B_ + b) * 32 * HW_;
    const float* bias = dir ? biasb : biasf;
    float* c = cst + (size_t)(dir * B_ + b) * 32 * HW_;
    float* outp = out + ((size_t)(t * B_ + b) * 64 + dir * 32) * HW_;
    const float* hprev = (t == 0) ? nullptr
                       : out + ((size_t)((t - 1) * B_ + b) * 64 + dir * 32) * HW_;
    const _Float16* wdir = wpk + (size_t)dir * 73728;

    __shared__ alignas(16) _Float16 lbuf[2 * NPOS * CI_PAD];  // 51,840 B
    _Float16* Bx = lbuf;
    _Float16* Bh = lbuf + NPOS * CI_PAD;

    const int tid = threadIdx.x;
    const int lane = tid & 63, wq = tid >> 6;

    f32x4 acc[4][8];
#pragma unroll
    for (int m = 0; m < 4; ++m)
#pragma unroll
        for (int nf = 0; nf < 8; ++nf) acc[m][nf] = (f32x4)(0.f);

    // Stage x-half (buffer Bx)
    stage_pos(Bx, xt, tid, x0, y0);
    if (tid < NPOS - 256) stage_pos(Bx, xt, tid + 256, x0, y0);

    // Prefetch h(t-1) for position tid into registers (overlaps barrier + x-compute)
    half8 hv[4];
    if (t > 0) {
        int r = tid / 18, cc = tid - r * 18;
        int gy = y0 + r - 1, gx = x0 + cc - 1;
        bool inb = ((unsigned)gy < 128u) && ((unsigned)gx < 128u);
        const float* g = hprev + (size_t)gy * W_ + gx;
#pragma unroll
        for (int cb = 0; cb < 4; ++cb) {
#pragma unroll
            for (int e = 0; e < 8; ++e)
                hv[cb][e] = (_Float16)(inb ? g[(cb * 8 + e) * HW_] : 0.f);
        }
    }
    __syncthreads();

    // x-half MFMAs (reads Bx); Bh writes below race with nothing.
    compute_half(acc, Bx, wdir, 0, lane, wq);

    if (t > 0) {
        _Float16* d = Bh + tid * CI_PAD;
#pragma unroll
        for (int cb = 0; cb < 4; ++cb) *(half8*)(d + cb * 8) = hv[cb];
        if (tid < NPOS - 256) stage_pos(Bh, hprev, tid + 256, x0, y0);
        __syncthreads();
        compute_half(acc, Bh, wdir, 1, lane, wq);
    }

    // Epilogue: lane-local. D row=(lane>>4)*4+reg -> pixel, col=lane&15 -> co within nf.
    const int q0 = lane & 15, px0 = (lane >> 4) * 4;
    float bI[2], bF[2], bO[2], bG[2];
#pragma unroll
    for (int qs = 0; qs < 2; ++qs) {
        bI[qs] = bias[qs * 16 + q0];
        bF[qs] = bias[32 + qs * 16 + q0];
        bO[qs] = bias[64 + qs * 16 + q0];
        bG[qs] = bias[96 + qs * 16 + q0];
    }
#pragma unroll
    for (int m = 0; m < 4; ++m) {
        int gy = y0 + wq * 4 + m;
#pragma unroll
        for (int qs = 0; qs < 2; ++qs) {
            int q = qs * 16 + q0;
            f32x4 zi = acc[m][qs], zf = acc[m][2 + qs], zo = acc[m][4 + qs], zg = acc[m][6 + qs];
            size_t off = (size_t)q * HW_ + (size_t)gy * W_ + x0 + px0;
            f32x4 cold = (f32x4)(0.f);
            if (t) cold = *(const f32x4*)(c + off);
            f32x4 cn, hn;
#pragma unroll
            for (int r = 0; r < 4; ++r) {
                float I = sigf(zi[r] + bI[qs]);
                float F = sigf(zf[r] + bF[qs]);
                float O = sigf(zo[r] + bO[qs]);
                float G = tanhf_(zg[r] + bG[qs]);
                float cnr = F * cold[r] + I * G;
                cn[r] = cnr;
                hn[r] = O * tanhf_(cnr);
            }
            *(f32x4*)(c + off) = cn;
            *(f32x4*)(outp + off) = hn;
        }
    }
}

extern "C" void kernel_launch(void* const* d_in, const int* in_sizes, int n_in,
                              void* d_out, int out_size, void* d_ws, size_t ws_size,
                              hipStream_t stream) {
    const float* x  = (const float*)d_in[0];
    const float* Wf = (const float*)d_in[1];
    const float* bf = (const float*)d_in[2];
    const float* Wb = (const float*)d_in[3];
    const float* bb = (const float*)d_in[4];
    float* out = (float*)d_out;
    char* ws = (char*)d_ws;

    _Float16* wpk = (_Float16*)ws;              // 294,912 B (2 x 147,456)
    float* cst = (float*)(ws + 294912);         // 16,777,216 B

    prep_pack<<<dim3(72), dim3(256), 0, stream>>>(Wf, Wb, wpk);

    for (int t = 0; t < S_; ++t) {
        convlstm_mfma<<<dim3(8, 8, 8), dim3(256), 0, stream>>>(
            x, wpk, bf, bb, cst, out, t);
    }
}

// Round 6
// 857.084 us; speedup vs baseline: 1.2915x; 1.2915x over previous
//
#include <hip/hip_runtime.h>

// BiCLSTM: S=16,B=4,Cin=32,Co=32,H=W=128. fp32 in/out.
// FP16 MFMA implicit-GEMM with ZERO in-step staging:
//  - x pre-converted once to per-tile A-operand layout [t][b][tile][pos324][ci32] fp16
//  - h written by epilogue directly into next step's A-tiles (ping-pong, halo scatter)
//  - no LDS, no __syncthreads in the step kernel; A/B stream from L2/L3.
#define S_ 16
#define B_ 4
#define H_ 128
#define W_ 128
#define HW_ (H_ * W_)
#define NPOS 324               // 18*18
#define TILE_ELEMS (NPOS * 32) // fp16 elems per (tile) A-block

typedef __attribute__((ext_vector_type(8))) _Float16 half8;
typedef __attribute__((ext_vector_type(4))) float f32x4;

__device__ __forceinline__ float sigf(float x) { return 1.f / (1.f + __expf(-x)); }
__device__ __forceinline__ float tanhf_(float x) { return 2.f / (1.f + __expf(-2.f * x)) - 1.f; }

// ---- B-fragment packing (same as r5): [dir][ks=18][nf=8][lane=64][e=8] fp16 ----
// ks = tap*2 + half; ci = half*32 + (lane>>4)*8 + e; co = nf*16 + (lane&15).
__global__ void prep_pack(const float* __restrict__ Wf, const float* __restrict__ Wb,
                          _Float16* __restrict__ wpk) {
    int id = blockIdx.x * 256 + threadIdx.x;  // 2*18*8*64 = 18432
    if (id >= 18432) return;
    int l = id & 63;
    int nf = (id >> 6) & 7;
    int ks = (id >> 9) % 18;
    int d = id / 9216;
    const float* Wsrc = d ? Wb : Wf;
    int tap = ks >> 1, half = ks & 1;
    int dy = tap / 3, dx = tap - dy * 3;
    int co = nf * 16 + (l & 15);
    _Float16* dst = wpk + (size_t)d * 73728 + ((size_t)(ks * 8 + nf) * 64 + l) * 8;
#pragma unroll
    for (int e = 0; e < 8; ++e) {
        int ci = half * 32 + (l >> 4) * 8 + e;
        dst[e] = (_Float16)Wsrc[((co * 64 + ci) * 3 + dy) * 3 + dx];
    }
}

// ---- One-time x -> tile layout: [ts][b][tile][pos][ci32] fp16 ----
__global__ void prep_xtiles(const float* __restrict__ x, _Float16* __restrict__ xt) {
    int id = blockIdx.x * 256 + threadIdx.x;  // 16*4*64*324 = 1,327,104
    if (id >= 16 * 4 * 64 * NPOS) return;
    int pos = id % NPOS;
    int u = id / NPOS;
    int tile = u & 63;
    u >>= 6;
    int b = u & 3;
    int ts = u >> 2;
    int r = pos / 18, cc = pos - r * 18;
    int gy = (tile >> 3) * 16 + r - 1;
    int gx = (tile & 7) * 16 + cc - 1;
    bool inb = ((unsigned)gy < 128u) && ((unsigned)gx < 128u);
    const float* g = x + ((size_t)(ts * 4 + b) * 32) * HW_ + (size_t)gy * W_ + gx;
    _Float16* dst = xt + (size_t)id * 32;
#pragma unroll
    for (int ci = 0; ci < 32; ++ci)
        dst[ci] = inb ? (_Float16)g[ci * HW_] : (_Float16)0.f;
}

__device__ __forceinline__ void kstep(f32x4 (&acc)[4][8], const _Float16* __restrict__ abase,
                                      const _Float16* __restrict__ bw, int ks,
                                      int px, int kg, int wq, int lane) {
    int tap = ks >> 1;
    int dy = tap / 3, dx = tap - dy * 3;
    half8 a[4];
#pragma unroll
    for (int m = 0; m < 4; ++m)
        a[m] = *(const half8*)(abase + ((size_t)((wq * 4 + m + dy) * 18 + px + dx)) * 32 + kg * 8);
    const _Float16* bp = bw + (size_t)ks * 4096;
#pragma unroll
    for (int nf = 0; nf < 8; ++nf) {
        half8 bfrag = *(const half8*)(bp + ((size_t)nf * 64 + lane) * 8);
#pragma unroll
        for (int m = 0; m < 4; ++m)
            acc[m][nf] = __builtin_amdgcn_mfma_f32_16x16x32_f16(a[m], bfrag, acc[m][nf], 0, 0, 0);
    }
}

// One timestep, both directions. grid (64, 8): x = tile, y = dir*4+b. 256 thr, no LDS.
__global__ __launch_bounds__(256, 2)
void convlstm_step(const _Float16* __restrict__ xtiles,
                   const _Float16* __restrict__ hin,    // read buffer (t-1), tile layout
                   _Float16* __restrict__ hout,         // write buffer (t), tile layout
                   const _Float16* __restrict__ wpk,
                   const float* __restrict__ biasf, const float* __restrict__ biasb,
                   float* __restrict__ cst, float* __restrict__ out, int t) {
    const int tile = blockIdx.x;
    const int dirb = blockIdx.y;
    const int dir = dirb >> 2, b = dirb & 3;
    const int ts = dir ? (S_ - 1 - t) : t;

    const _Float16* base_x = xtiles + ((size_t)(ts * 4 + b) * 64 + tile) * TILE_ELEMS;
    const _Float16* base_h = hin + ((size_t)dirb * 64 + tile) * TILE_ELEMS;
    _Float16* hob = hout + (size_t)dirb * 64 * TILE_ELEMS;  // per (dir,b); tile offset added per write
    const _Float16* bw = wpk + (size_t)dir * 73728;
    const float* bias = dir ? biasb : biasf;
    float* cbase = cst + (size_t)dirb * 32 * HW_;
    float* outp = out + ((size_t)(t * 4 + b) * 64 + dir * 32) * HW_;

    const int tid = threadIdx.x;
    const int lane = tid & 63, wq = tid >> 6;
    const int px = lane & 15, kg = lane >> 4;

    f32x4 acc[4][8];
#pragma unroll
    for (int m = 0; m < 4; ++m)
#pragma unroll
        for (int nf = 0; nf < 8; ++nf) acc[m][nf] = (f32x4)(0.f);

    if (t == 0) {
#pragma unroll 1
        for (int tap = 0; tap < 9; ++tap)
            kstep(acc, base_x, bw, tap * 2, px, kg, wq, lane);
    } else {
#pragma unroll 1
        for (int tap = 0; tap < 9; ++tap) {
            kstep(acc, base_x, bw, tap * 2, px, kg, wq, lane);
            kstep(acc, base_h, bw, tap * 2 + 1, px, kg, wq, lane);
        }
    }

    // Epilogue. D: col=lane&15 -> co(q within nf-pair), row=(lane>>4)*4+reg -> gx.
    const int q0 = px;                 // co low index
    const int gx0 = (tile & 7) * 16, gy0 = (tile >> 3) * 16;
    const int tx = tile & 7, ty_ = tile >> 3;
    const int lx0 = kg * 4;            // local x of acc reg 0

    float bI[2], bF[2], bO[2], bG[2];
#pragma unroll
    for (int qs = 0; qs < 2; ++qs) {
        bI[qs] = bias[qs * 16 + q0];
        bF[qs] = bias[32 + qs * 16 + q0];
        bO[qs] = bias[64 + qs * 16 + q0];
        bG[qs] = bias[96 + qs * 16 + q0];
    }
#pragma unroll
    for (int m = 0; m < 4; ++m) {
        const int ly = wq * 4 + m;     // local y 0..15
        const int gy = gy0 + ly;
#pragma unroll
        for (int qs = 0; qs < 2; ++qs) {
            const int q = qs * 16 + q0;
            f32x4 zi = acc[m][qs], zf = acc[m][2 + qs], zo = acc[m][4 + qs], zg = acc[m][6 + qs];
            size_t off = (size_t)q * HW_ + (size_t)gy * W_ + gx0 + lx0;
            f32x4 cold = (f32x4)(0.f);
            if (t) cold = *(const f32x4*)(cbase + off);
            f32x4 cn, hn;
#pragma unroll
            for (int r = 0; r < 4; ++r) {
                float I = sigf(zi[r] + bI[qs]);
                float F = sigf(zf[r] + bF[qs]);
                float O = sigf(zo[r] + bO[qs]);
                float G = tanhf_(zg[r] + bG[qs]);
                float cnr = F * cold[r] + I * G;
                cn[r] = cnr;
                hn[r] = O * tanhf_(cnr);
            }
            *(f32x4*)(cbase + off) = cn;
            *(f32x4*)(outp + off) = hn;
            // Scatter h(t) fp16 into tile-format write buffer (own + halo neighbors).
#pragma unroll
            for (int r = 0; r < 4; ++r) {
                _Float16 hh = (_Float16)hn[r];
                int lx = lx0 + r;
                hob[((size_t)tile) * TILE_ELEMS + (size_t)((ly + 1) * 18 + lx + 1) * 32 + q] = hh;
                bool Le = (lx == 0) && (tx > 0);
                bool Re = (lx == 15) && (tx < 7);
                bool Te = (ly == 0) && (ty_ > 0);
                bool Be = (ly == 15) && (ty_ < 7);
                if (Le) hob[((size_t)tile - 1) * TILE_ELEMS + (size_t)((ly + 1) * 18 + 17) * 32 + q] = hh;
                if (Re) hob[((size_t)tile + 1) * TILE_ELEMS + (size_t)((ly + 1) * 18 + 0) * 32 + q] = hh;
                if (Te) hob[((size_t)tile - 8) * TILE_ELEMS + (size_t)(17 * 18 + lx + 1) * 32 + q] = hh;
                if (Be) hob[((size_t)tile + 8) * TILE_ELEMS + (size_t)(0 * 18 + lx + 1) * 32 + q] = hh;
                if (Te && Le) hob[((size_t)tile - 9) * TILE_ELEMS + (size_t)(17 * 18 + 17) * 32 + q] = hh;
                if (Te && Re) hob[((size_t)tile - 7) * TILE_ELEMS + (size_t)(17 * 18 + 0) * 32 + q] = hh;
                if (Be && Le) hob[((size_t)tile + 7) * TILE_ELEMS + (size_t)(0 * 18 + 17) * 32 + q] = hh;
                if (Be && Re) hob[((size_t)tile + 9) * TILE_ELEMS + (size_t)(0 * 18 + 0) * 32 + q] = hh;
            }
        }
    }
}

extern "C" void kernel_launch(void* const* d_in, const int* in_sizes, int n_in,
                              void* d_out, int out_size, void* d_ws, size_t ws_size,
                              hipStream_t stream) {
    const float* x  = (const float*)d_in[0];
    const float* Wf = (const float*)d_in[1];
    const float* bf = (const float*)d_in[2];
    const float* Wb = (const float*)d_in[3];
    const float* bb = (const float*)d_in[4];
    float* out = (float*)d_out;
    char* ws = (char*)d_ws;

    // ws layout (bytes)
    const size_t OFF_WPK = 0;                       // 294,912
    const size_t OFF_XT  = 327680;                  // 84,934,656
    const size_t OFF_H0  = OFF_XT + 84934656;       // 10,616,832
    const size_t OFF_H1  = OFF_H0 + 10616832;       // 10,616,832
    const size_t OFF_C   = OFF_H1 + 10616832;       // 16,777,216

    _Float16* wpk = (_Float16*)(ws + OFF_WPK);
    _Float16* xt  = (_Float16*)(ws + OFF_XT);
    _Float16* hb[2] = { (_Float16*)(ws + OFF_H0), (_Float16*)(ws + OFF_H1) };
    float* cst = (float*)(ws + OFF_C);

    // Zero h ping-pong buffers (halo slots outside the image must read as 0).
    hipMemsetAsync(ws + OFF_H0, 0, 2u * 10616832u, stream);

    prep_pack<<<dim3(72), dim3(256), 0, stream>>>(Wf, Wb, wpk);
    prep_xtiles<<<dim3(5184), dim3(256), 0, stream>>>(x, xt);

    for (int t = 0; t < S_; ++t) {
        convlstm_step<<<dim3(64, 8), dim3(256), 0, stream>>>(
            xt, hb[(t + 1) & 1], hb[t & 1], wpk, bf, bb, cst, out, t);
    }
}

// Round 7
// 660.031 us; speedup vs baseline: 1.6771x; 1.2985x over previous
//
#include <hip/hip_runtime.h>

// BiCLSTM: S=16,B=4,Cin=32,Co=32,H=W=128. fp32 in/out.
// FP16 MFMA implicit-GEMM, zero in-step staging:
//  - x pre-tiled once to A-operand layout [t][b][tile][pos324][ci32] fp16 (coalesced v2)
//  - h written by epilogue directly into next step's A-tiles (ping-pong, halo scatter)
//  - step K-loop software-pipelined: B-frag double-buffer + early A loads.
#define S_ 16
#define B_ 4
#define H_ 128
#define W_ 128
#define HW_ (H_ * W_)
#define NPOS 324               // 18*18
#define TILE_ELEMS (NPOS * 32) // fp16 elems per tile A-block

typedef __attribute__((ext_vector_type(8))) _Float16 half8;
typedef __attribute__((ext_vector_type(4))) float f32x4;

__device__ __forceinline__ float sigf(float x) { return 1.f / (1.f + __expf(-x)); }
__device__ __forceinline__ float tanhf_(float x) { return 2.f / (1.f + __expf(-2.f * x)) - 1.f; }

// ---- B-fragment packing: [dir][ks=18][nf=8][lane=64][e=8] fp16 ----
// ks = tap*2 + half; ci = half*32 + (lane>>4)*8 + e; co = nf*16 + (lane&15).
__global__ void prep_pack(const float* __restrict__ Wf, const float* __restrict__ Wb,
                          _Float16* __restrict__ wpk) {
    int id = blockIdx.x * 256 + threadIdx.x;  // 2*18*8*64 = 18432
    if (id >= 18432) return;
    int l = id & 63;
    int nf = (id >> 6) & 7;
    int ks = (id >> 9) % 18;
    int d = id / 9216;
    const float* Wsrc = d ? Wb : Wf;
    int tap = ks >> 1, half = ks & 1;
    int dy = tap / 3, dx = tap - dy * 3;
    int co = nf * 16 + (l & 15);
    _Float16* dst = wpk + (size_t)d * 73728 + ((size_t)(ks * 8 + nf) * 64 + l) * 8;
#pragma unroll
    for (int e = 0; e < 8; ++e) {
        int ci = half * 32 + (l >> 4) * 8 + e;
        dst[e] = (_Float16)Wsrc[((co * 64 + ci) * 3 + dy) * 3 + dx];
    }
}

// ---- One-time x -> tile layout, coalesced: 4 threads/pos, one half8 store each ----
__global__ void prep_xtiles(const float* __restrict__ x, _Float16* __restrict__ xt) {
    int id = blockIdx.x * 256 + threadIdx.x;  // 16*4*64*324*4 = 5,308,416
    if (id >= 16 * 4 * 64 * NPOS * 4) return;
    int cb = id & 3;
    int u = id >> 2;           // [ts][b][tile][pos]
    int pos = u % NPOS;
    int v = u / NPOS;
    int tile = v & 63;
    v >>= 6;
    int b = v & 3;
    int ts = v >> 2;
    int r = pos / 18, cc = pos - r * 18;
    int gy = (tile >> 3) * 16 + r - 1;
    int gx = (tile & 7) * 16 + cc - 1;
    bool inb = ((unsigned)gy < 128u) && ((unsigned)gx < 128u);
    const float* g = x + ((size_t)(ts * 4 + b) * 32 + cb * 8) * HW_ + (size_t)gy * W_ + gx;
    half8 vv;
#pragma unroll
    for (int e = 0; e < 8; ++e)
        vv[e] = inb ? (_Float16)g[e * HW_] : (_Float16)0.f;
    *(half8*)(xt + (size_t)u * 32 + cb * 8) = vv;
}

// A-frag loader: row band (wq*4+m+dy), col px+dx, kg-th 8-ci chunk.
__device__ __forceinline__ half8 lda(const _Float16* __restrict__ base, int m, int dy,
                                     int dx, int px, int kg, int wq) {
    return *(const half8*)(base + (size_t)(((wq * 4 + m + dy) * 18) + px + dx) * 32 + kg * 8);
}
__device__ __forceinline__ half8 ldb(const _Float16* __restrict__ bw, int ks, int nf, int lane) {
    return *(const half8*)(bw + (size_t)(ks * 8 + nf) * 512 + lane * 8);
}

// One timestep, both directions. grid (64, 8): x = tile, y = dir*4+b. 256 thr, no LDS.
__global__ __launch_bounds__(256, 2)
void convlstm_step(const _Float16* __restrict__ xtiles,
                   const _Float16* __restrict__ hin,    // read buffer (t-1), tile layout
                   _Float16* __restrict__ hout,         // write buffer (t), tile layout
                   const _Float16* __restrict__ wpk,
                   const float* __restrict__ biasf, const float* __restrict__ biasb,
                   float* __restrict__ cst, float* __restrict__ out, int t) {
    const int tile = blockIdx.x;
    const int dirb = blockIdx.y;
    const int dir = dirb >> 2, b = dirb & 3;
    const int ts = dir ? (S_ - 1 - t) : t;

    const _Float16* base_x = xtiles + ((size_t)(ts * 4 + b) * 64 + tile) * TILE_ELEMS;
    const _Float16* base_h = hin + ((size_t)dirb * 64 + tile) * TILE_ELEMS;
    _Float16* hob = hout + (size_t)dirb * 64 * TILE_ELEMS;
    const _Float16* bw = wpk + (size_t)dir * 73728;
    const float* bias = dir ? biasb : biasf;
    float* cbase = cst + (size_t)dirb * 32 * HW_;
    float* outp = out + ((size_t)(t * 4 + b) * 64 + dir * 32) * HW_;

    const int tid = threadIdx.x;
    const int lane = tid & 63, wq = tid >> 6;
    const int px = lane & 15, kg = lane >> 4;

    f32x4 acc[4][8];
#pragma unroll
    for (int m = 0; m < 4; ++m)
#pragma unroll
        for (int nf = 0; nf < 8; ++nf) acc[m][nf] = (f32x4)(0.f);

    if (t == 0) {
        // x-half only (h(-1)=0): simple loop, cold path (1/16 of steps).
#pragma unroll 1
        for (int tap = 0; tap < 9; ++tap) {
            int dy = tap / 3, dx = tap - dy * 3;
            half8 a[4];
#pragma unroll
            for (int m = 0; m < 4; ++m) a[m] = lda(base_x, m, dy, dx, px, kg, wq);
#pragma unroll
            for (int nf = 0; nf < 8; ++nf) {
                half8 bb8 = ldb(bw, tap * 2, nf, lane);
#pragma unroll
                for (int m = 0; m < 4; ++m)
                    acc[m][nf] = __builtin_amdgcn_mfma_f32_16x16x32_f16(a[m], bb8, acc[m][nf], 0, 0, 0);
            }
        }
    } else {
        // Software-pipelined: B double-buffered, A loaded one MFMA-group ahead.
        half8 bcur[8], bnxt[8];
        half8 ax[4], ah[4];
#pragma unroll
        for (int nf = 0; nf < 8; ++nf) bcur[nf] = ldb(bw, 0, nf, lane);
        {
            int dy = 0, dx = 0;
#pragma unroll
            for (int m = 0; m < 4; ++m) ax[m] = lda(base_x, m, dy, dx, px, kg, wq);
        }
#pragma unroll 1
        for (int tap = 0; tap < 9; ++tap) {
            const int dy = tap / 3, dx = tap - dy * 3;
            // prefetch: odd-ks B (h-half of this tap) + h A-frags
#pragma unroll
            for (int nf = 0; nf < 8; ++nf) bnxt[nf] = ldb(bw, tap * 2 + 1, nf, lane);
#pragma unroll
            for (int m = 0; m < 4; ++m) ah[m] = lda(base_h, m, dy, dx, px, kg, wq);
            // x-half MFMAs (covers latency of the loads above)
#pragma unroll
            for (int nf = 0; nf < 8; ++nf)
#pragma unroll
                for (int m = 0; m < 4; ++m)
                    acc[m][nf] = __builtin_amdgcn_mfma_f32_16x16x32_f16(ax[m], bcur[nf], acc[m][nf], 0, 0, 0);
            // prefetch: next tap's even-ks B + x A-frags
            if (tap < 8) {
                const int tn = tap + 1;
                const int dy2 = tn / 3, dx2 = tn - dy2 * 3;
#pragma unroll
                for (int nf = 0; nf < 8; ++nf) bcur[nf] = ldb(bw, tn * 2, nf, lane);
#pragma unroll
                for (int m = 0; m < 4; ++m) ax[m] = lda(base_x, m, dy2, dx2, px, kg, wq);
            }
            // h-half MFMAs
#pragma unroll
            for (int nf = 0; nf < 8; ++nf)
#pragma unroll
                for (int m = 0; m < 4; ++m)
                    acc[m][nf] = __builtin_amdgcn_mfma_f32_16x16x32_f16(ah[m], bnxt[nf], acc[m][nf], 0, 0, 0);
        }
    }

    // Epilogue. D: col=lane&15 -> co(q within nf-pair), row=(lane>>4)*4+reg -> gx.
    const int q0 = px;
    const int gx0 = (tile & 7) * 16, gy0 = (tile >> 3) * 16;
    const int tx = tile & 7, ty_ = tile >> 3;
    const int lx0 = kg * 4;

    float bI[2], bF[2], bO[2], bG[2];
#pragma unroll
    for (int qs = 0; qs < 2; ++qs) {
        bI[qs] = bias[qs * 16 + q0];
        bF[qs] = bias[32 + qs * 16 + q0];
        bO[qs] = bias[64 + qs * 16 + q0];
        bG[qs] = bias[96 + qs * 16 + q0];
    }
#pragma unroll
    for (int m = 0; m < 4; ++m) {
        const int ly = wq * 4 + m;
        const int gy = gy0 + ly;
#pragma unroll
        for (int qs = 0; qs < 2; ++qs) {
            const int q = qs * 16 + q0;
            f32x4 zi = acc[m][qs], zf = acc[m][2 + qs], zo = acc[m][4 + qs], zg = acc[m][6 + qs];
            size_t off = (size_t)q * HW_ + (size_t)gy * W_ + gx0 + lx0;
            f32x4 cold = (f32x4)(0.f);
            if (t) cold = *(const f32x4*)(cbase + off);
            f32x4 cn, hn;
#pragma unroll
            for (int r = 0; r < 4; ++r) {
                float I = sigf(zi[r] + bI[qs]);
                float F = sigf(zf[r] + bF[qs]);
                float O = sigf(zo[r] + bO[qs]);
                float G = tanhf_(zg[r] + bG[qs]);
                float cnr = F * cold[r] + I * G;
                cn[r] = cnr;
                hn[r] = O * tanhf_(cnr);
            }
            *(f32x4*)(cbase + off) = cn;
            *(f32x4*)(outp + off) = hn;
            // Scatter h(t) fp16 into tile-format write buffer (own + halo neighbors).
#pragma unroll
            for (int r = 0; r < 4; ++r) {
                _Float16 hh = (_Float16)hn[r];
                int lx = lx0 + r;
                hob[((size_t)tile) * TILE_ELEMS + (size_t)((ly + 1) * 18 + lx + 1) * 32 + q] = hh;
                bool Le = (lx == 0) && (tx > 0);
                bool Re = (lx == 15) && (tx < 7);
                bool Te = (ly == 0) && (ty_ > 0);
                bool Be = (ly == 15) && (ty_ < 7);
                if (Le) hob[((size_t)tile - 1) * TILE_ELEMS + (size_t)((ly + 1) * 18 + 17) * 32 + q] = hh;
                if (Re) hob[((size_t)tile + 1) * TILE_ELEMS + (size_t)((ly + 1) * 18 + 0) * 32 + q] = hh;
                if (Te) hob[((size_t)tile - 8) * TILE_ELEMS + (size_t)(17 * 18 + lx + 1) * 32 + q] = hh;
                if (Be) hob[((size_t)tile + 8) * TILE_ELEMS + (size_t)(0 * 18 + lx + 1) * 32 + q] = hh;
                if (Te && Le) hob[((size_t)tile - 9) * TILE_ELEMS + (size_t)(17 * 18 + 17) * 32 + q] = hh;
                if (Te && Re) hob[((size_t)tile - 7) * TILE_ELEMS + (size_t)(17 * 18 + 0) * 32 + q] = hh;
                if (Be && Le) hob[((size_t)tile + 7) * TILE_ELEMS + (size_t)(0 * 18 + 17) * 32 + q] = hh;
                if (Be && Re) hob[((size_t)tile + 9) * TILE_ELEMS + (size_t)(0 * 18 + 0) * 32 + q] = hh;
            }
        }
    }
}

extern "C" void kernel_launch(void* const* d_in, const int* in_sizes, int n_in,
                              void* d_out, int out_size, void* d_ws, size_t ws_size,
                              hipStream_t stream) {
    const float* x  = (const float*)d_in[0];
    const float* Wf = (const float*)d_in[1];
    const float* bf = (const float*)d_in[2];
    const float* Wb = (const float*)d_in[3];
    const float* bb = (const float*)d_in[4];
    float* out = (float*)d_out;
    char* ws = (char*)d_ws;

    const size_t OFF_WPK = 0;                       // 294,912
    const size_t OFF_XT  = 327680;                  // 84,934,656
    const size_t OFF_H0  = OFF_XT + 84934656;       // 10,616,832
    const size_t OFF_H1  = OFF_H0 + 10616832;       // 10,616,832
    const size_t OFF_C   = OFF_H1 + 10616832;       // 16,777,216

    _Float16* wpk = (_Float16*)(ws + OFF_WPK);
    _Float16* xt  = (_Float16*)(ws + OFF_XT);
    _Float16* hb[2] = { (_Float16*)(ws + OFF_H0), (_Float16*)(ws + OFF_H1) };
    float* cst = (float*)(ws + OFF_C);

    // Zero h ping-pong buffers (halo slots outside the image must read as 0).
    hipMemsetAsync(ws + OFF_H0, 0, 2u * 10616832u, stream);

    prep_pack<<<dim3(72), dim3(256), 0, stream>>>(Wf, Wb, wpk);
    prep_xtiles<<<dim3(20736), dim3(256), 0, stream>>>(x, xt);

    for (int t = 0; t < S_; ++t) {
        convlstm_step<<<dim3(64, 8), dim3(256), 0, stream>>>(
            xt, hb[(t + 1) & 1], hb[t & 1], wpk, bf, bb, cst, out, t);
    }
}

// Round 8
// 649.887 us; speedup vs baseline: 1.7033x; 1.0156x over previous
//
#include <hip/hip_runtime.h>

// BiCLSTM: S=16,B=4,Cin=32,Co=32,H=W=128. fp32 in/out.
// FP16 MFMA implicit-GEMM:
//  - x pre-tiled once to A-operand layout [t][b][tile][pos324][ci32] fp16
//  - h written by epilogue directly into next step's A-tiles (ping-pong, halo scatter)
//  - B weight fragments staged via global_load_lds, double-buffered; A prefetched in regs.
#define S_ 16
#define B_ 4
#define H_ 128
#define W_ 128
#define HW_ (H_ * W_)
#define NPOS 324               // 18*18
#define TILE_ELEMS (NPOS * 32) // fp16 elems per tile A-block

typedef __attribute__((ext_vector_type(8))) _Float16 half8;
typedef __attribute__((ext_vector_type(4))) float f32x4;

__device__ __forceinline__ float sigf(float x) { return 1.f / (1.f + __expf(-x)); }
__device__ __forceinline__ float tanhf_(float x) { return 2.f / (1.f + __expf(-2.f * x)) - 1.f; }

__device__ __forceinline__ void gl2lds16(const _Float16* g, _Float16* l) {
    __builtin_amdgcn_global_load_lds(
        (const __attribute__((address_space(1))) unsigned int*)g,
        (__attribute__((address_space(3))) unsigned int*)l, 16, 0, 0);
}

// ---- B-fragment packing: [dir][ks=18][nf=8][lane=64][e=8] fp16 ----
// ks = tap*2 + half; ci = half*32 + (lane>>4)*8 + e; co = nf*16 + (lane&15).
__global__ void prep_pack(const float* __restrict__ Wf, const float* __restrict__ Wb,
                          _Float16* __restrict__ wpk) {
    int id = blockIdx.x * 256 + threadIdx.x;  // 2*18*8*64 = 18432
    if (id >= 18432) return;
    int l = id & 63;
    int nf = (id >> 6) & 7;
    int ks = (id >> 9) % 18;
    int d = id / 9216;
    const float* Wsrc = d ? Wb : Wf;
    int tap = ks >> 1, half = ks & 1;
    int dy = tap / 3, dx = tap - dy * 3;
    int co = nf * 16 + (l & 15);
    _Float16* dst = wpk + (size_t)d * 73728 + ((size_t)(ks * 8 + nf) * 64 + l) * 8;
#pragma unroll
    for (int e = 0; e < 8; ++e) {
        int ci = half * 32 + (l >> 4) * 8 + e;
        dst[e] = (_Float16)Wsrc[((co * 64 + ci) * 3 + dy) * 3 + dx];
    }
}

// ---- One-time x -> tile layout, coalesced: 4 threads/pos, one half8 store each ----
__global__ void prep_xtiles(const float* __restrict__ x, _Float16* __restrict__ xt) {
    int id = blockIdx.x * 256 + threadIdx.x;  // 16*4*64*324*4 = 5,308,416
    if (id >= 16 * 4 * 64 * NPOS * 4) return;
    int cb = id & 3;
    int u = id >> 2;           // [ts][b][tile][pos]
    int pos = u % NPOS;
    int v = u / NPOS;
    int tile = v & 63;
    v >>= 6;
    int b = v & 3;
    int ts = v >> 2;
    int r = pos / 18, cc = pos - r * 18;
    int gy = (tile >> 3) * 16 + r - 1;
    int gx = (tile & 7) * 16 + cc - 1;
    bool inb = ((unsigned)gy < 128u) && ((unsigned)gx < 128u);
    const float* g = x + ((size_t)(ts * 4 + b) * 32 + cb * 8) * HW_ + (size_t)gy * W_ + gx;
    half8 vv;
#pragma unroll
    for (int e = 0; e < 8; ++e)
        vv[e] = inb ? (_Float16)g[e * HW_] : (_Float16)0.f;
    *(half8*)(xt + (size_t)u * 32 + cb * 8) = vv;
}

// A-frag loader: row band (wq*4+m+dy), col px+dx, kg-th 8-ci chunk.
__device__ __forceinline__ half8 lda(const _Float16* __restrict__ base, int m, int dy,
                                     int dx, int px, int kg, int wq) {
    return *(const half8*)(base + (size_t)(((wq * 4 + m + dy) * 18) + px + dx) * 32 + kg * 8);
}
__device__ __forceinline__ half8 ldb(const _Float16* __restrict__ bw, int ks, int nf, int lane) {
    return *(const half8*)(bw + (size_t)(ks * 8 + nf) * 512 + lane * 8);
}

// One timestep, both directions. grid (64, 8): x = tile, y = dir*4+b.
__global__ __launch_bounds__(256, 2)
void convlstm_step(const _Float16* __restrict__ xtiles,
                   const _Float16* __restrict__ hin,    // read buffer (t-1), tile layout
                   _Float16* __restrict__ hout,         // write buffer (t), tile layout
                   const _Float16* __restrict__ wpk,
                   const float* __restrict__ biasf, const float* __restrict__ biasb,
                   float* __restrict__ cst, float* __restrict__ out, int t) {
    const int tile = blockIdx.x;
    const int dirb = blockIdx.y;
    const int dir = dirb >> 2, b = dirb & 3;
    const int ts = dir ? (S_ - 1 - t) : t;

    const _Float16* base_x = xtiles + ((size_t)(ts * 4 + b) * 64 + tile) * TILE_ELEMS;
    const _Float16* base_h = hin + ((size_t)dirb * 64 + tile) * TILE_ELEMS;
    _Float16* hob = hout + (size_t)dirb * 64 * TILE_ELEMS;
    const _Float16* bw = wpk + (size_t)dir * 73728;
    const float* bias = dir ? biasb : biasf;
    float* cbase = cst + (size_t)dirb * 32 * HW_;
    float* outp = out + ((size_t)(t * 4 + b) * 64 + dir * 32) * HW_;

    __shared__ alignas(16) _Float16 bsh[2][8][64][8];  // 16 KiB, double-buffered B frags

    const int tid = threadIdx.x;
    const int lane = tid & 63, wq = tid >> 6;
    const int px = lane & 15, kg = lane >> 4;

    f32x4 acc[4][8];
#pragma unroll
    for (int m = 0; m < 4; ++m)
#pragma unroll
        for (int nf = 0; nf < 8; ++nf) acc[m][nf] = (f32x4)(0.f);

    if (t == 0) {
        // x-half only (h(-1)=0): direct-from-L1 path, cold (1/16 of steps).
#pragma unroll 1
        for (int tap = 0; tap < 9; ++tap) {
            int dy = tap / 3, dx = tap - dy * 3;
            half8 a[4];
#pragma unroll
            for (int m = 0; m < 4; ++m) a[m] = lda(base_x, m, dy, dx, px, kg, wq);
#pragma unroll
            for (int nf = 0; nf < 8; ++nf) {
                half8 bb8 = ldb(bw, tap * 2, nf, lane);
#pragma unroll
                for (int m = 0; m < 4; ++m)
                    acc[m][nf] = __builtin_amdgcn_mfma_f32_16x16x32_f16(a[m], bb8, acc[m][nf], 0, 0, 0);
            }
        }
    } else {
        // Pipelined: B(ks) in LDS (global_load_lds, double-buffer), A(ks) in regs (ping-pong).
        half8 aP[4], aQ[4];
        {
            // stage B(0) -> buf 0; load A(0) -> aP
            const _Float16* gs = bw + ((size_t)(0 * 8 + wq * 2) * 64 + lane) * 8;
            gl2lds16(gs, &bsh[0][wq * 2][0][0]);
            gl2lds16(gs + 512, &bsh[0][wq * 2 + 1][0][0]);
#pragma unroll
            for (int m = 0; m < 4; ++m) aP[m] = lda(base_x, m, 0, 0, px, kg, wq);
        }

        auto body = [&](int ks, half8(&acur)[4], half8(&anxt)[4]) {
            __syncthreads();  // B(ks) staged+visible; buf[(ks+1)&1] reads (iter ks-1) done
            if (ks < 17) {
                const int ksn = ks + 1;
                const _Float16* gs = bw + ((size_t)(ksn * 8 + wq * 2) * 64 + lane) * 8;
                gl2lds16(gs, &bsh[ksn & 1][wq * 2][0][0]);
                gl2lds16(gs + 512, &bsh[ksn & 1][wq * 2 + 1][0][0]);
                const int tapn = ksn >> 1;
                const int dyn_ = tapn / 3, dxn = tapn - dyn_ * 3;
                const _Float16* an = (ksn & 1) ? base_h : base_x;
#pragma unroll
                for (int m = 0; m < 4; ++m) anxt[m] = lda(an, m, dyn_, dxn, px, kg, wq);
            }
            const _Float16* lb = &bsh[ks & 1][0][0][0];
#pragma unroll
            for (int nf = 0; nf < 8; ++nf) {
                half8 bb8 = *(const half8*)(lb + nf * 512 + lane * 8);
#pragma unroll
                for (int m = 0; m < 4; ++m)
                    acc[m][nf] = __builtin_amdgcn_mfma_f32_16x16x32_f16(acur[m], bb8, acc[m][nf], 0, 0, 0);
            }
        };
#pragma unroll 1
        for (int ks = 0; ks < 18; ks += 2) {
            body(ks, aP, aQ);
            body(ks + 1, aQ, aP);
        }
    }

    // Epilogue. D: col=lane&15 -> co(q within nf-pair), row=(lane>>4)*4+reg -> px.
    const int q0 = px;
    const int gx0 = (tile & 7) * 16, gy0 = (tile >> 3) * 16;
    const int tx = tile & 7, ty_ = tile >> 3;
    const int lx0 = kg * 4;

    float bI[2], bF[2], bO[2], bG[2];
#pragma unroll
    for (int qs = 0; qs < 2; ++qs) {
        bI[qs] = bias[qs * 16 + q0];
        bF[qs] = bias[32 + qs * 16 + q0];
        bO[qs] = bias[64 + qs * 16 + q0];
        bG[qs] = bias[96 + qs * 16 + q0];
    }
#pragma unroll
    for (int m = 0; m < 4; ++m) {
        const int ly = wq * 4 + m;
        const int gy = gy0 + ly;
#pragma unroll
        for (int qs = 0; qs < 2; ++qs) {
            const int q = qs * 16 + q0;
            f32x4 zi = acc[m][qs], zf = acc[m][2 + qs], zo = acc[m][4 + qs], zg = acc[m][6 + qs];
            size_t off = (size_t)q * HW_ + (size_t)gy * W_ + gx0 + lx0;
            f32x4 cold = (f32x4)(0.f);
            if (t) cold = *(const f32x4*)(cbase + off);
            f32x4 cn, hn;
#pragma unroll
            for (int r = 0; r < 4; ++r) {
                float I = sigf(zi[r] + bI[qs]);
                float F = sigf(zf[r] + bF[qs]);
                float O = sigf(zo[r] + bO[qs]);
                float G = tanhf_(zg[r] + bG[qs]);
                float cnr = F * cold[r] + I * G;
                cn[r] = cnr;
                hn[r] = O * tanhf_(cnr);
            }
            *(f32x4*)(cbase + off) = cn;
            *(f32x4*)(outp + off) = hn;
            // Scatter h(t) fp16 into tile-format write buffer (own + halo neighbors).
#pragma unroll
            for (int r = 0; r < 4; ++r) {
                _Float16 hh = (_Float16)hn[r];
                int lx = lx0 + r;
                hob[((size_t)tile) * TILE_ELEMS + (size_t)((ly + 1) * 18 + lx + 1) * 32 + q] = hh;
                bool Le = (lx == 0) && (tx > 0);
                bool Re = (lx == 15) && (tx < 7);
                bool Te = (ly == 0) && (ty_ > 0);
                bool Be = (ly == 15) && (ty_ < 7);
                if (Le) hob[((size_t)tile - 1) * TILE_ELEMS + (size_t)((ly + 1) * 18 + 17) * 32 + q] = hh;
                if (Re) hob[((size_t)tile + 1) * TILE_ELEMS + (size_t)((ly + 1) * 18 + 0) * 32 + q] = hh;
                if (Te) hob[((size_t)tile - 8) * TILE_ELEMS + (size_t)(17 * 18 + lx + 1) * 32 + q] = hh;
                if (Be) hob[((size_t)tile + 8) * TILE_ELEMS + (size_t)(0 * 18 + lx + 1) * 32 + q] = hh;
                if (Te && Le) hob[((size_t)tile - 9) * TILE_ELEMS + (size_t)(17 * 18 + 17) * 32 + q] = hh;
                if (Te && Re) hob[((size_t)tile - 7) * TILE_ELEMS + (size_t)(17 * 18 + 0) * 32 + q] = hh;
                if (Be && Le) hob[((size_t)tile + 7) * TILE_ELEMS + (size_t)(0 * 18 + 17) * 32 + q] = hh;
                if (Be && Re) hob[((size_t)tile + 9) * TILE_ELEMS + (size_t)(0 * 18 + 0) * 32 + q] = hh;
            }
        }
    }
}

extern "C" void kernel_launch(void* const* d_in, const int* in_sizes, int n_in,
                              void* d_out, int out_size, void* d_ws, size_t ws_size,
                              hipStream_t stream) {
    const float* x  = (const float*)d_in[0];
    const float* Wf = (const float*)d_in[1];
    const float* bf = (const float*)d_in[2];
    const float* Wb = (const float*)d_in[3];
    const float* bb = (const float*)d_in[4];
    float* out = (float*)d_out;
    char* ws = (char*)d_ws;

    const size_t OFF_WPK = 0;                       // 294,912
    const size_t OFF_XT  = 327680;                  // 84,934,656
    const size_t OFF_H0  = OFF_XT + 84934656;       // 10,616,832
    const size_t OFF_H1  = OFF_H0 + 10616832;       // 10,616,832
    const size_t OFF_C   = OFF_H1 + 10616832;       // 16,777,216

    _Float16* wpk = (_Float16*)(ws + OFF_WPK);
    _Float16* xt  = (_Float16*)(ws + OFF_XT);
    _Float16* hb[2] = { (_Float16*)(ws + OFF_H0), (_Float16*)(ws + OFF_H1) };
    float* cst = (float*)(ws + OFF_C);

    // Zero h ping-pong buffers (halo slots outside the image must read as 0).
    hipMemsetAsync(ws + OFF_H0, 0, 2u * 10616832u, stream);

    prep_pack<<<dim3(72), dim3(256), 0, stream>>>(Wf, Wb, wpk);
    prep_xtiles<<<dim3(20736), dim3(256), 0, stream>>>(x, xt);

    for (int t = 0; t < S_; ++t) {
        convlstm_step<<<dim3(64, 8), dim3(256), 0, stream>>>(
            xt, hb[(t + 1) & 1], hb[t & 1], wpk, bf, bb, cst, out, t);
    }
}